// Round 1
// baseline (1267.845 us; speedup 1.0000x reference)
//
#include <hip/hip_runtime.h>

#define N_IN 8192
#define N_OUT 8192

typedef float f4 __attribute__((ext_vector_type(4)));
typedef int   i4 __attribute__((ext_vector_type(4)));

// ---------------------------------------------------------------------------
// kd: dense matvec out[o] = bias[o] + dot(weight[o,:], x * (1-sat)).
// One wave per output row, 4 waves/block, 2048 blocks. Saturation mask
// applied inline (x/sat are 32 KiB broadcasts, L1/L2-resident); weight is
// streamed once -> nontemporal. unroll 8 => 8 x 16B weight loads in flight
// per lane. Plain store preserves the previous version's exact dense bits.
// ---------------------------------------------------------------------------
__global__ __launch_bounds__(256) void kd_dense(
    const float* __restrict__ weight, const float* __restrict__ bias,
    const float* __restrict__ x, const int* __restrict__ sat,
    float* __restrict__ out)
{
    int wave = threadIdx.x >> 6;
    int lane = threadIdx.x & 63;
    int o = blockIdx.x * 4 + wave;

    const f4* wrow = (const f4*)(weight + (size_t)o * N_IN);
    const f4* xv   = (const f4*)x;
    const i4* sv   = (const i4*)sat;

    float sum = 0.0f;
#pragma unroll 8
    for (int it = 0; it < N_IN / 4 / 64; ++it) {   // 32 iters
        int idx = it * 64 + lane;
        f4 w = __builtin_nontemporal_load(wrow + idx);
        f4 v = xv[idx];
        i4 s = sv[idx];
        float vx = s.x ? 0.0f : v.x;
        float vy = s.y ? 0.0f : v.y;
        float vz = s.z ? 0.0f : v.z;
        float vw = s.w ? 0.0f : v.w;
        sum += w.x * vx + w.y * vy + w.z * vz + w.w * vw;
    }
#pragma unroll
    for (int off = 32; off; off >>= 1) sum += __shfl_down(sum, off);
    if (lane == 0) out[o] = bias[o] + sum;
}

// ---------------------------------------------------------------------------
// kb: bud accumulation. Grid = 8 o-tiles x 128 k-chunks = 1024 blocks.
// Phase 1 (wave 0): compute h2[k] for the block's 64 k's from x/W1/b1/W2/b2
// directly (replaces the old k1_prep kernel + h2buf round-trip), ballot-
// compact the ACTIVE k's into an LDS list. Phase 2 (all 256 threads):
// branch-free loop over nact entries; per entry each thread owns 4 outputs
// (3 aligned float4 of W3 + 1 float4 of b3, nontemporal), unroll 4 so the
// compiler batches 16 independent global loads (256 B/lane in flight).
// Inactive k's generate zero HBM traffic, same as the old wave-uniform skip.
// Partial sums land in out via hw fp32 atomics (stream-ordered after kd).
// ---------------------------------------------------------------------------
__global__ __launch_bounds__(256) void kb_bud(
    const float* __restrict__ x, const int* __restrict__ sat,
    const float* __restrict__ W1, const float* __restrict__ b1,
    const float* __restrict__ W2, const float* __restrict__ b2,
    const float* __restrict__ W3, const float* __restrict__ b3,
    float* __restrict__ out)
{
    __shared__ f4  sh2[64];
    __shared__ int slist[64];
    __shared__ int snact;

    int otile  = blockIdx.x & 7;    // 8 tiles of 1024 outputs
    int kchunk = blockIdx.x >> 3;   // 128 chunks of 64 inputs
    int k0  = kchunk * 64;
    int tid = threadIdx.x;

    if (tid < 64) {                 // wave 0 exactly
        int k = k0 + tid;
        float xs = x[k];
        bool s = (sat[k] != 0);

        const float* w1 = W1 + (size_t)k * 9;
        const float* B1 = b1 + (size_t)k * 3;
        float x3 = xs * (1.0f / 3.0f);
        float h1[3];
#pragma unroll
        for (int i = 0; i < 3; ++i) {
            float v = x3 * (w1[3*i] + w1[3*i+1] + w1[3*i+2]) + B1[i];
            h1[i] = v > 0.0f ? v : 0.0f;
        }
        const float* w2 = W2 + (size_t)k * 9;
        const float* B2 = b2 + (size_t)k * 3;
        float h2[3];
#pragma unroll
        for (int i = 0; i < 3; ++i) {
            float v = w2[3*i] * h1[0] + w2[3*i+1] * h1[1] + w2[3*i+2] * h1[2] + B2[i];
            h2[i] = v > 0.0f ? v : 0.0f;
        }

        bool act = s && (xs != 0.0f);
        unsigned long long m = __ballot(act);
        if (act) {
            int pos = __popcll(m & ((1ull << tid) - 1ull));
            slist[pos] = tid;       // ascending k order preserved
        }
        if (tid == 0) snact = __popcll(m);
        f4 hv; hv.x = h2[0]; hv.y = h2[1]; hv.z = h2[2]; hv.w = 0.0f;
        sh2[tid] = hv;
    }
    __syncthreads();

    int nact = snact;               // wave-uniform
    int o = otile * 1024 + tid * 4;
    float acc0 = 0.0f, acc1 = 0.0f, acc2 = 0.0f, acc3 = 0.0f;

#pragma unroll 4
    for (int j = 0; j < nact; ++j) {
        int kk = slist[j];
        f4 h = sh2[kk];
        size_t base = (size_t)(k0 + kk) * N_OUT + o;
        const f4* wp = (const f4*)(W3 + base * 3);
        f4 a  = __builtin_nontemporal_load(wp);
        f4 b  = __builtin_nontemporal_load(wp + 1);
        f4 c  = __builtin_nontemporal_load(wp + 2);
        f4 bb = __builtin_nontemporal_load((const f4*)(b3 + base));

        float t0 = h.x * a.x + h.y * a.y + h.z * a.z + bb.x;
        float t1 = h.x * a.w + h.y * b.x + h.z * b.y + bb.y;
        float t2 = h.x * b.z + h.y * b.w + h.z * c.x + bb.z;
        float t3 = h.x * c.y + h.y * c.z + h.z * c.w + bb.w;
        acc0 += t0 > 0.0f ? t0 : 0.0f;
        acc1 += t1 > 0.0f ? t1 : 0.0f;
        acc2 += t2 > 0.0f ? t2 : 0.0f;
        acc3 += t3 > 0.0f ? t3 : 0.0f;
    }

    unsafeAtomicAdd(out + o + 0, acc0);
    unsafeAtomicAdd(out + o + 1, acc1);
    unsafeAtomicAdd(out + o + 2, acc2);
    unsafeAtomicAdd(out + o + 3, acc3);
}

extern "C" void kernel_launch(void* const* d_in, const int* in_sizes, int n_in,
                              void* d_out, int out_size, void* d_ws, size_t ws_size,
                              hipStream_t stream)
{
    const float* x    = (const float*)d_in[0];
    const int*   sat  = (const int*)  d_in[1];
    const float* wgt  = (const float*)d_in[2];
    const float* bias = (const float*)d_in[3];
    const float* W1   = (const float*)d_in[4];
    const float* b1   = (const float*)d_in[5];
    const float* W2   = (const float*)d_in[6];
    const float* b2   = (const float*)d_in[7];
    const float* W3   = (const float*)d_in[8];
    const float* b3   = (const float*)d_in[9];
    float* out = (float*)d_out;

    kd_dense<<<N_OUT / 4, 256, 0, stream>>>(wgt, bias, x, sat, out);
    kb_bud<<<1024, 256, 0, stream>>>(x, sat, W1, b1, W2, b2, W3, b3, out);
}